// Round 10
// baseline (36.544 us; speedup 1.0000x reference)
//
#include <hip/hip_runtime.h>
#include <math.h>

// GumbelSampler: iterative gumbel-softmax k-hot (k=64) over 256 rows of 16384,
// then straight-through hard top-64.
//
// Round-10: SPLIT into two dispatches for per-phase attribution (and to
// decouple the screen pipeline from the serial dynamics):
//   K1 screen (grid 256 x 1024): load -> f0-bit histogram -> cutoff ->
//      prefix-ordered compaction -> write 256 padded (f0,idx)/row to d_ws;
//      then all waves zero-fill the output. 4 barriers, no dynamics wait.
//   K2 dynamics (grid 256 x 256): wave0 runs the 64-iter ex-space dynamics
//      (bit-identical candidate order to round 9), 1 barrier, 256-thread
//      exact parallel rank (lax.top_k tie semantics) writes the 64 ones
//      (ordered after K1's zeros by dispatch order).
// Rebase headroom widened 10->90 bits (exact po2 scaling; oh unchanged).
// Selection math is value-identical to rounds 7-9 (absmax 0.0 throughout).

#define NWAVES  16
#define M_ELEMS 16384
#define EPT     16
#define KSEL    64
#define NCAND   256
#define CPL     4
#define NBINS   4096                // transformed f0 bits >> 20
#define THRESH  (M_ELEMS - NCAND)   // 16128: cut where CntLT >= THRESH
#define C10     14.42695019f        // log2(e)/tau

// ---- DPP wave64 helpers ----
template <int CTRL, int RM = 0xF>
__device__ __forceinline__ float dpp_f(float x, float identity) {
    return __int_as_float(__builtin_amdgcn_update_dpp(
        __float_as_int(identity), __float_as_int(x), CTRL, RM, 0xF, false));
}
template <int CTRL, int RM = 0xF>
__device__ __forceinline__ unsigned dpp_u(unsigned x, unsigned identity) {
    return (unsigned)__builtin_amdgcn_update_dpp(
        (int)identity, (int)x, CTRL, RM, 0xF, false);
}
__device__ __forceinline__ float wave_sum_bcast(float x) {
    x += dpp_f<0x111>(x, 0.0f);
    x += dpp_f<0x112>(x, 0.0f);
    x += dpp_f<0x114>(x, 0.0f);
    x += dpp_f<0x118>(x, 0.0f);
    x += dpp_f<0x142>(x, 0.0f);
    x += dpp_f<0x143>(x, 0.0f);
    return __int_as_float(__builtin_amdgcn_readlane(__float_as_int(x), 63));
}
__device__ __forceinline__ float wave_fmax_bcast(float x) {
    x = fmaxf(x, dpp_f<0x111>(x, -INFINITY));
    x = fmaxf(x, dpp_f<0x112>(x, -INFINITY));
    x = fmaxf(x, dpp_f<0x114>(x, -INFINITY));
    x = fmaxf(x, dpp_f<0x118>(x, -INFINITY));
    x = fmaxf(x, dpp_f<0x142>(x, -INFINITY));
    x = fmaxf(x, dpp_f<0x143>(x, -INFINITY));
    return __int_as_float(__builtin_amdgcn_readlane(__float_as_int(x), 63));
}
__device__ __forceinline__ unsigned wave_prefix_incl(unsigned x) {
    x += dpp_u<0x111>(x, 0u);
    x += dpp_u<0x112>(x, 0u);
    x += dpp_u<0x114>(x, 0u);
    x += dpp_u<0x118>(x, 0u);
    x += dpp_u<0x142, 0xA>(x, 0u);     // row_bcast:15 -> rows 1,3
    x += dpp_u<0x143, 0xC>(x, 0u);     // row_bcast:31 -> rows 2,3
    return x;
}

// ======================= K1: screen =======================
__global__ __launch_bounds__(1024, 4) void screen_kernel(
    const float* __restrict__ scores,
    const float* __restrict__ gumbel,
    float* __restrict__ cand_f,
    unsigned* __restrict__ cand_i,
    float* __restrict__ out)
{
    const int tid  = threadIdx.x;
    const int lane = tid & 63;
    const int wid  = tid >> 6;
    const int bid = blockIdx.x;
    const int r   = ((bid & 127) << 1) | (bid >> 7);   // e-pair XCD swizzle
    const int t_ = r >> 7;
    const int be = r & 127;
    const int b  = be >> 1;
    const int e  = be & 1;

    __shared__ unsigned int hist[NBINS];
    __shared__ unsigned int wofs[NWAVES];
    __shared__ unsigned int cutbin;
    __shared__ unsigned int candcnt;

    float* orow = out + (size_t)(t_ * 64 + b) * (M_ELEMS * 2) + e;

    // ---- load; element k=g*4+j -> m = tid*4 + j + g*4096 ----
    float fv[EPT];
    {
        const float* gum = gumbel + (size_t)r * M_ELEMS;
        const float* scb = scores + (size_t)b * (M_ELEMS * 2);
        #pragma unroll
        for (int g = 0; g < 4; ++g) {
            const int mb = (tid << 2) + (g << 12);
            const float4 gv = *reinterpret_cast<const float4*>(&gum[mb]);
            const float4 sa = *reinterpret_cast<const float4*>(&scb[(size_t)mb * 2]);
            const float4 sb = *reinterpret_cast<const float4*>(&scb[(size_t)mb * 2 + 4]);
            float s0, s1, s2, s3;
            if (e == 0) { s0 = sa.x; s1 = sa.z; s2 = sb.x; s3 = sb.z; }
            else        { s0 = sa.y; s1 = sa.w; s2 = sb.y; s3 = sb.w; }
            fv[g * 4 + 0] = s0 + gv.x;
            fv[g * 4 + 1] = s1 + gv.y;
            fv[g * 4 + 2] = s2 + gv.z;
            fv[g * 4 + 3] = s3 + gv.w;
        }
    }
    #pragma unroll
    for (int k = 0; k < NBINS / 1024; ++k) hist[tid + k * 1024] = 0u;
    __syncthreads();                                   // B1

    // ---- histogram of monotone-transformed f0 bits ----
    #pragma unroll
    for (int k = 0; k < EPT; ++k) {
        const unsigned u  = __float_as_uint(fv[k]);
        const unsigned tk = u ^ (unsigned)(((int)u >> 31) | 0x80000000);
        atomicAdd(&hist[tk >> 20], 1u);
    }
    __syncthreads();                                   // B2

    // ---- wave0 cutoff: min bin B with CntLT(B) >= 16128 ----
    if (wid == 0) {
        unsigned part = 0;
        #pragma unroll 8
        for (int j = 0; j < 64; ++j)                   // rotated: bank-spread
            part += hist[(lane << 6) + ((j + lane) & 63)];
        const unsigned P = wave_prefix_incl(part);
        const unsigned long long mk = __ballot(P >= THRESH);
        const int L = __builtin_ctzll(mk);
        const unsigned base = (L > 0)
            ? (unsigned)__builtin_amdgcn_readlane((int)P, L - 1) : 0u;
        const unsigned h2 = hist[(L << 6) + lane];
        const unsigned p2 = wave_prefix_incl(h2) + base;
        const unsigned long long mk2 = __ballot(p2 >= THRESH);
        const int j2 = __builtin_ctzll(mk2);
        if (lane == 0) {
            cutbin  = (unsigned)((L << 6) + j2 + 1);
            candcnt = M_ELEMS - (unsigned)__builtin_amdgcn_readlane((int)p2, j2);
        }
    }
    __syncthreads();                                   // B3
    const unsigned cutKey = cutbin << 20;
    const unsigned nc     = candcnt;

    // ---- prefix-ordered compaction, straight to global d_ws ----
    unsigned mycnt = 0, hitm = 0;
    #pragma unroll
    for (int k = 0; k < EPT; ++k) {
        const unsigned u  = __float_as_uint(fv[k]);
        const unsigned tk = u ^ (unsigned)(((int)u >> 31) | 0x80000000);
        const bool c = tk >= cutKey;
        hitm |= (c ? 1u : 0u) << k;
        mycnt += c ? 1u : 0u;
    }
    const unsigned inc = wave_prefix_incl(mycnt);
    if (lane == 63) wofs[wid] = inc;
    __syncthreads();                                   // B4
    unsigned wbase = 0;
    #pragma unroll
    for (int i = 0; i < NWAVES; ++i) wbase += (i < wid) ? wofs[i] : 0u;
    unsigned slot = wbase + inc - mycnt;
    float*    cfr = cand_f + (size_t)r * NCAND;
    unsigned* cir = cand_i + (size_t)r * NCAND;
    #pragma unroll
    for (int k = 0; k < EPT; ++k) {
        if ((hitm >> k) & 1u) {
            cfr[slot] = fv[k];
            cir[slot] = (unsigned)((tid << 2) + (k & 3) + ((k >> 2) << 12));
            ++slot;
        }
    }
    if ((unsigned)tid >= nc && tid < NCAND) {          // pad [nc, 256)
        cfr[tid] = -INFINITY;                          // -> ex = 0 exactly
        cir[tid] = 0x7fffffffu;
    }

    // ---- zero-fill this row's output (all 16 waves) ----
    #pragma unroll
    for (int k = 0; k < EPT; ++k)
        orow[(size_t)(tid + (k << 10)) * 2] = 0.0f;
}

// ======================= K2: dynamics + rank =======================
__global__ __launch_bounds__(256, 8) void dyn_kernel(
    const float* __restrict__ cand_f,
    const unsigned* __restrict__ cand_i,
    float* __restrict__ out)
{
    const int tid  = threadIdx.x;
    const int lane = tid & 63;
    const int wid  = tid >> 6;
    const int r    = blockIdx.x;
    const int t_ = r >> 7;
    const int be = r & 127;
    const int b  = be >> 1;
    const int e  = be & 1;

    __shared__ __align__(16) float    khbuf[NCAND];
    __shared__ __align__(16) unsigned idxb[NCAND];

    float* orow = out + (size_t)(t_ * 64 + b) * (M_ELEMS * 2) + e;

    idxb[tid] = cand_i[(size_t)r * NCAND + tid];       // coalesced

    if (wid == 0) {
        float cf[CPL], cex[CPL], ckh[CPL];
        #pragma unroll
        for (int k = 0; k < CPL; ++k)
            cf[k] = cand_f[(size_t)r * NCAND + lane + (k << 6)];
        float cmax = fmaxf(fmaxf(cf[0], cf[1]), fmaxf(cf[2], cf[3]));
        cmax = wave_fmax_bcast(cmax);                  // row max (always cand)
        const float nbw = fmaf(-cmax, C10, 100.0f);    // top ex = 2^100
        #pragma unroll
        for (int k = 0; k < CPL; ++k) {
            cex[k] = __builtin_amdgcn_exp2f(fmaf(cf[k], C10, nbw));
            ckh[k] = 0.0f;
        }
        for (int it = 0; it < KSEL; ++it) {
            float gsum = wave_sum_bcast((cex[0] + cex[1]) + (cex[2] + cex[3]));
            // exponent-range rebase: 90 bits of headroom -> ~1x per row
            const int eb = (int)((__float_as_uint(gsum) >> 23) & 0xFF);
            if (eb < 127 + 10) {                       // gsum < 2^10
                int sh = 354 - eb;                     // rescale gsum -> ~2^100
                if (sh > 254) sh = 254;
                const float s = __uint_as_float((unsigned)sh << 23);
                #pragma unroll
                for (int k = 0; k < CPL; ++k) cex[k] *= s;
                gsum = wave_sum_bcast((cex[0] + cex[1]) + (cex[2] + cex[3]));
                if (!(gsum > 0.0f)) gsum = INFINITY;
            }
            const float rsum = __builtin_amdgcn_rcpf(gsum);
            #pragma unroll
            for (int k = 0; k < CPL; ++k) {
                ckh[k] = fmaf(cex[k], rsum, ckh[k]);          // kh += oh
                const float t  = fmaf(-cex[k], rsum, 1.0f);   // 1 - oh
                const float t2 = t * t;
                const float t4 = t2 * t2;
                const float t8 = t4 * t4;
                cex[k] = cex[k] * t8 * t2;                    // ex *= t^10
            }
        }
        #pragma unroll
        for (int k = 0; k < CPL; ++k) khbuf[lane + (k << 6)] = ckh[k];
    }
    __syncthreads();                                   // kh + idx visible

    // ---- exact parallel top-64 by rank (lax.top_k tie semantics) ----
    const float    myv = khbuf[tid];
    const unsigned myi = idxb[tid];
    unsigned rank = 0;
    #pragma unroll 8
    for (int j = 0; j < NCAND; j += 4) {
        const float4 v  = *reinterpret_cast<const float4*>(&khbuf[j]);
        const uint4  ii = *reinterpret_cast<const uint4*>(&idxb[j]);
        rank += (v.x > myv || (v.x == myv && ii.x < myi)) ? 1u : 0u;
        rank += (v.y > myv || (v.y == myv && ii.y < myi)) ? 1u : 0u;
        rank += (v.z > myv || (v.z == myv && ii.z < myi)) ? 1u : 0u;
        rank += (v.w > myv || (v.w == myv && ii.w < myi)) ? 1u : 0u;
    }
    if (rank < KSEL && myi < M_ELEMS)
        orow[(size_t)myi * 2] = 1.0f;
}

extern "C" void kernel_launch(void* const* d_in, const int* in_sizes, int n_in,
                              void* d_out, int out_size, void* d_ws, size_t ws_size,
                              hipStream_t stream) {
    const float* scores = (const float*)d_in[0];
    const float* gumbel = (const float*)d_in[1];
    float* out = (float*)d_out;
    const int rows = in_sizes[1] / M_ELEMS;   // 256
    float*    cand_f = (float*)d_ws;
    unsigned* cand_i = (unsigned*)d_ws + (size_t)rows * NCAND;
    screen_kernel<<<rows, 1024, 0, stream>>>(scores, gumbel, cand_f, cand_i, out);
    dyn_kernel<<<rows, 256, 0, stream>>>(cand_f, cand_i, out);
}

// Round 11
// 34.179 us; speedup vs baseline: 1.0692x; 1.0692x over previous
//
#include <hip/hip_runtime.h>
#include <math.h>

// GumbelSampler: iterative gumbel-softmax k-hot (k=64) over 256 rows of 16384,
// then straight-through hard top-64.
//
// Round-11: CO-RESIDENCY. R10's split showed the ~20us residual is not phase
// coupling; with grid=256 (1 block/CU) every latency is naked. K1 becomes
// 512 blocks x 512 threads -> 2 blocks/CU (16 waves, 32KB LDS), each block
// screening HALF a row (8192 elems) to its LOCAL top-128. Global top-128 is
// a subset of the union of local top-128s; ever-warm set ~top-80 (validated
// envelope since R5); excluded-tail gsum perturbation <= e^-7 relative.
// K2 (R10's validated dynamics + exact parallel rank) reads the 256-candidate
// union per row, unchanged.
//
// Ordering: K1 writes all zeros; K2 writes the 64 ones -> ordered by the
// kernel boundary. XCD swizzle keeps e-pair half-blocks co-XCD for L2 merge
// of the interleaved stride-2 zero writes.

#define M_ELEMS 16384
#define HALF_N  8192
#define EPT     16                  // elements per thread (both kernels' phases)
#define KSEL    64
#define NCL     128                 // local candidates per half-row
#define NCAND   256                 // union per row (K2)
#define CPL     4
#define NBINS   4096                // transformed f0 bits >> 20
#define THRESH_L (HALF_N - NCL)     // 8064: cut where CntLT >= THRESH_L
#define C10     14.42695019f        // log2(e)/tau

// ---- DPP wave64 helpers ----
template <int CTRL, int RM = 0xF>
__device__ __forceinline__ float dpp_f(float x, float identity) {
    return __int_as_float(__builtin_amdgcn_update_dpp(
        __float_as_int(identity), __float_as_int(x), CTRL, RM, 0xF, false));
}
template <int CTRL, int RM = 0xF>
__device__ __forceinline__ unsigned dpp_u(unsigned x, unsigned identity) {
    return (unsigned)__builtin_amdgcn_update_dpp(
        (int)identity, (int)x, CTRL, RM, 0xF, false);
}
__device__ __forceinline__ float wave_sum_bcast(float x) {
    x += dpp_f<0x111>(x, 0.0f);
    x += dpp_f<0x112>(x, 0.0f);
    x += dpp_f<0x114>(x, 0.0f);
    x += dpp_f<0x118>(x, 0.0f);
    x += dpp_f<0x142>(x, 0.0f);
    x += dpp_f<0x143>(x, 0.0f);
    return __int_as_float(__builtin_amdgcn_readlane(__float_as_int(x), 63));
}
__device__ __forceinline__ float wave_fmax_bcast(float x) {
    x = fmaxf(x, dpp_f<0x111>(x, -INFINITY));
    x = fmaxf(x, dpp_f<0x112>(x, -INFINITY));
    x = fmaxf(x, dpp_f<0x114>(x, -INFINITY));
    x = fmaxf(x, dpp_f<0x118>(x, -INFINITY));
    x = fmaxf(x, dpp_f<0x142>(x, -INFINITY));
    x = fmaxf(x, dpp_f<0x143>(x, -INFINITY));
    return __int_as_float(__builtin_amdgcn_readlane(__float_as_int(x), 63));
}
__device__ __forceinline__ unsigned wave_prefix_incl(unsigned x) {
    x += dpp_u<0x111>(x, 0u);
    x += dpp_u<0x112>(x, 0u);
    x += dpp_u<0x114>(x, 0u);
    x += dpp_u<0x118>(x, 0u);
    x += dpp_u<0x142, 0xA>(x, 0u);     // row_bcast:15 -> rows 1,3
    x += dpp_u<0x143, 0xC>(x, 0u);     // row_bcast:31 -> rows 2,3
    return x;
}

// ======================= K1: half-row screen (512 x 512) =======================
__global__ __launch_bounds__(512, 4) void screen_kernel(
    const float* __restrict__ scores,
    const float* __restrict__ gumbel,
    float* __restrict__ cand_f,
    unsigned* __restrict__ cand_i,
    float* __restrict__ out)
{
    const int tid  = threadIdx.x;
    const int lane = tid & 63;
    const int wid  = tid >> 6;          // 0..7
    const int bid  = blockIdx.x;        // 0..511
    // p encodes the row (e-pair swizzle: partner rows 128 apart -> same XCD),
    // top bit selects the half.
    const int p    = bid & 255;
    const int half = bid >> 8;
    const int r    = ((p & 127) << 1) | (p >> 7);
    const int t_ = r >> 7;
    const int be = r & 127;
    const int b  = be >> 1;
    const int e  = be & 1;

    __shared__ unsigned int hist[NBINS];   // 16 KB -> 2 blocks/CU fit
    __shared__ unsigned int wofs[8];
    __shared__ unsigned int cutbin;
    __shared__ unsigned int candcnt;

    float* orow = out + (size_t)(t_ * 64 + b) * (M_ELEMS * 2) + e;

    // ---- load 8192 elems; k=g*4+j -> m = half*8192 + tid*4 + j + g*2048 ----
    float fv[EPT];
    {
        const float* gum = gumbel + (size_t)r * M_ELEMS;
        const float* scb = scores + (size_t)b * (M_ELEMS * 2);
        #pragma unroll
        for (int g = 0; g < 4; ++g) {
            const int mb = (half << 13) + (tid << 2) + (g << 11);
            const float4 gv = *reinterpret_cast<const float4*>(&gum[mb]);
            const float4 sa = *reinterpret_cast<const float4*>(&scb[(size_t)mb * 2]);
            const float4 sb = *reinterpret_cast<const float4*>(&scb[(size_t)mb * 2 + 4]);
            float s0, s1, s2, s3;
            if (e == 0) { s0 = sa.x; s1 = sa.z; s2 = sb.x; s3 = sb.z; }
            else        { s0 = sa.y; s1 = sa.w; s2 = sb.y; s3 = sb.w; }
            fv[g * 4 + 0] = s0 + gv.x;
            fv[g * 4 + 1] = s1 + gv.y;
            fv[g * 4 + 2] = s2 + gv.z;
            fv[g * 4 + 3] = s3 + gv.w;
        }
    }
    #pragma unroll
    for (int k = 0; k < NBINS / 512; ++k) hist[tid + k * 512] = 0u;
    __syncthreads();                                   // B1

    // ---- histogram of monotone-transformed f0 bits ----
    #pragma unroll
    for (int k = 0; k < EPT; ++k) {
        const unsigned u  = __float_as_uint(fv[k]);
        const unsigned tk = u ^ (unsigned)(((int)u >> 31) | 0x80000000);
        atomicAdd(&hist[tk >> 20], 1u);
    }
    __syncthreads();                                   // B2

    // ---- wave0 cutoff: min bin B with CntLT(B) >= 8064 ----
    if (wid == 0) {
        unsigned part = 0;
        #pragma unroll 8
        for (int j = 0; j < 64; ++j)                   // rotated: bank-spread
            part += hist[(lane << 6) + ((j + lane) & 63)];
        const unsigned P = wave_prefix_incl(part);
        const unsigned long long mk = __ballot(P >= THRESH_L);
        const int L = __builtin_ctzll(mk);
        const unsigned base = (L > 0)
            ? (unsigned)__builtin_amdgcn_readlane((int)P, L - 1) : 0u;
        const unsigned h2 = hist[(L << 6) + lane];
        const unsigned p2 = wave_prefix_incl(h2) + base;
        const unsigned long long mk2 = __ballot(p2 >= THRESH_L);
        const int j2 = __builtin_ctzll(mk2);
        if (lane == 0) {
            cutbin  = (unsigned)((L << 6) + j2 + 1);
            candcnt = HALF_N - (unsigned)__builtin_amdgcn_readlane((int)p2, j2);
        }
    }
    __syncthreads();                                   // B3
    const unsigned cutKey = cutbin << 20;
    const unsigned nc     = candcnt;                   // <= 128

    // ---- prefix-ordered compaction to d_ws[r*256 + half*128 ...] ----
    unsigned mycnt = 0, hitm = 0;
    #pragma unroll
    for (int k = 0; k < EPT; ++k) {
        const unsigned u  = __float_as_uint(fv[k]);
        const unsigned tk = u ^ (unsigned)(((int)u >> 31) | 0x80000000);
        const bool c = tk >= cutKey;
        hitm |= (c ? 1u : 0u) << k;
        mycnt += c ? 1u : 0u;
    }
    const unsigned inc = wave_prefix_incl(mycnt);
    if (lane == 63) wofs[wid] = inc;
    __syncthreads();                                   // B4
    unsigned wbase = 0;
    #pragma unroll
    for (int i = 0; i < 8; ++i) wbase += (i < wid) ? wofs[i] : 0u;
    unsigned slot = wbase + inc - mycnt;
    const size_t cbase = (size_t)r * NCAND + (size_t)half * NCL;
    #pragma unroll
    for (int k = 0; k < EPT; ++k) {
        if ((hitm >> k) & 1u) {
            cand_f[cbase + slot] = fv[k];
            cand_i[cbase + slot] =
                (unsigned)((half << 13) + (tid << 2) + (k & 3) + ((k >> 2) << 11));
            ++slot;
        }
    }
    if ((unsigned)tid >= nc && tid < NCL) {            // pad [nc, 128)
        cand_f[cbase + tid] = -INFINITY;               // -> ex = 0 exactly
        cand_i[cbase + tid] = 0x7fffffffu;
    }

    // ---- zero-fill this half-row's output residues ----
    #pragma unroll
    for (int k = 0; k < EPT; ++k) {
        const int m = (half << 13) + tid + (k << 9);
        orow[(size_t)m * 2] = 0.0f;
    }
}

// ======================= K2: dynamics + rank (256 x 256) =======================
__global__ __launch_bounds__(256, 8) void dyn_kernel(
    const float* __restrict__ cand_f,
    const unsigned* __restrict__ cand_i,
    float* __restrict__ out)
{
    const int tid  = threadIdx.x;
    const int lane = tid & 63;
    const int wid  = tid >> 6;
    const int r    = blockIdx.x;
    const int t_ = r >> 7;
    const int be = r & 127;
    const int b  = be >> 1;
    const int e  = be & 1;

    __shared__ __align__(16) float    khbuf[NCAND];
    __shared__ __align__(16) unsigned idxb[NCAND];

    float* orow = out + (size_t)(t_ * 64 + b) * (M_ELEMS * 2) + e;

    idxb[tid] = cand_i[(size_t)r * NCAND + tid];       // coalesced

    if (wid == 0) {
        float cf[CPL], cex[CPL], ckh[CPL];
        #pragma unroll
        for (int k = 0; k < CPL; ++k)
            cf[k] = cand_f[(size_t)r * NCAND + lane + (k << 6)];
        float cmax = fmaxf(fmaxf(cf[0], cf[1]), fmaxf(cf[2], cf[3]));
        cmax = wave_fmax_bcast(cmax);                  // row max (always cand)
        const float nbw = fmaf(-cmax, C10, 100.0f);    // top ex = 2^100
        #pragma unroll
        for (int k = 0; k < CPL; ++k) {
            cex[k] = __builtin_amdgcn_exp2f(fmaf(cf[k], C10, nbw));
            ckh[k] = 0.0f;
        }
        for (int it = 0; it < KSEL; ++it) {
            float gsum = wave_sum_bcast((cex[0] + cex[1]) + (cex[2] + cex[3]));
            // exponent-range rebase: 90 bits of headroom -> ~1x per row
            const int eb = (int)((__float_as_uint(gsum) >> 23) & 0xFF);
            if (eb < 127 + 10) {                       // gsum < 2^10
                int sh = 354 - eb;                     // rescale gsum -> ~2^100
                if (sh > 254) sh = 254;
                const float s = __uint_as_float((unsigned)sh << 23);
                #pragma unroll
                for (int k = 0; k < CPL; ++k) cex[k] *= s;
                gsum = wave_sum_bcast((cex[0] + cex[1]) + (cex[2] + cex[3]));
                if (!(gsum > 0.0f)) gsum = INFINITY;
            }
            const float rsum = __builtin_amdgcn_rcpf(gsum);
            #pragma unroll
            for (int k = 0; k < CPL; ++k) {
                ckh[k] = fmaf(cex[k], rsum, ckh[k]);          // kh += oh
                const float t  = fmaf(-cex[k], rsum, 1.0f);   // 1 - oh
                const float t2 = t * t;
                const float t4 = t2 * t2;
                const float t8 = t4 * t4;
                cex[k] = cex[k] * t8 * t2;                    // ex *= t^10
            }
        }
        #pragma unroll
        for (int k = 0; k < CPL; ++k) khbuf[lane + (k << 6)] = ckh[k];
    }
    __syncthreads();                                   // kh + idx visible

    // ---- exact parallel top-64 by rank (lax.top_k tie semantics) ----
    const float    myv = khbuf[tid];
    const unsigned myi = idxb[tid];
    unsigned rank = 0;
    #pragma unroll 8
    for (int j = 0; j < NCAND; j += 4) {
        const float4 v  = *reinterpret_cast<const float4*>(&khbuf[j]);
        const uint4  ii = *reinterpret_cast<const uint4*>(&idxb[j]);
        rank += (v.x > myv || (v.x == myv && ii.x < myi)) ? 1u : 0u;
        rank += (v.y > myv || (v.y == myv && ii.y < myi)) ? 1u : 0u;
        rank += (v.z > myv || (v.z == myv && ii.z < myi)) ? 1u : 0u;
        rank += (v.w > myv || (v.w == myv && ii.w < myi)) ? 1u : 0u;
    }
    if (rank < KSEL && myi < M_ELEMS)
        orow[(size_t)myi * 2] = 1.0f;
}

extern "C" void kernel_launch(void* const* d_in, const int* in_sizes, int n_in,
                              void* d_out, int out_size, void* d_ws, size_t ws_size,
                              hipStream_t stream) {
    const float* scores = (const float*)d_in[0];
    const float* gumbel = (const float*)d_in[1];
    float* out = (float*)d_out;
    const int rows = in_sizes[1] / M_ELEMS;   // 256
    float*    cand_f = (float*)d_ws;
    unsigned* cand_i = (unsigned*)d_ws + (size_t)rows * NCAND;
    screen_kernel<<<rows * 2, 512, 0, stream>>>(scores, gumbel, cand_f, cand_i, out);
    dyn_kernel<<<rows, 256, 0, stream>>>(cand_f, cand_i, out);
}